// Round 3
// baseline (282.955 us; speedup 1.0000x reference)
//
#include <hip/hip_runtime.h>
#include <math.h>

// Folded model (exact algebra, per-token):
//   h      = relu(x @ G1 + b11)                      [400 MACs]
//   g      = relu(h @ P1 + x @ P2 + F2)              [800 MACs]
//   logits = g @ M2 + h @ Q1 + x @ Q2 + F3           [180 MACs]
//   out    = softmax(logits)
// Weight layouts padded so every LDS weight access is a ds_read_b128.

#define OFF_G1   0      // [20][20] row k (x index)
#define OFF_P1   400    // [20][20] row m' (h index)
#define OFF_P2   800    // [20][20] row k (x index)
#define OFF_Q1   1200   // [20][4]  row m' : {Q1[m'][0..2], 0}
#define OFF_Q2   1280   // [20][4]  row k
#define OFF_M2   1360   // [20][4]  row m (g index)
#define OFF_B11  1440   // [20]
#define OFF_F2   1460   // [20]
#define OFF_F3   1480   // [4] {f3[0..2], 0}
#define NW       1484
// scratch (in d_ws, beyond the weight block)
#define OFF_G2   1536   // [20][20] G2[i][m]
#define OFF_M3   1936   // [20][3]  M3[i][c]
#define OFF_E1   1996   // [20]

// ---- prep1: layer-1 folds into d_ws scratch ----
__global__ void prep1_kernel(const float* __restrict__ Wv, const float* __restrict__ Wres,
                             const float* __restrict__ W1, const float* __restrict__ b2,
                             const float* __restrict__ b3, const float* __restrict__ Wc,
                             const float* __restrict__ W3, float* __restrict__ W) {
    const int idx = threadIdx.x;
    if (idx < 400) {
        const int i = idx / 20, m = idx % 20;
        float s = 0.f;
        for (int j = 0; j < 20; ++j)
            s = fmaf(Wv[400 + j*20 + i] + Wres[400 + i*20 + j], W1[400 + m*20 + j], s);
        W[OFF_G2 + idx] = s;
    } else if (idx < 460) {
        const int r = idx - 400, i = r / 3, c = r % 3;
        float s = 0.f;
        for (int p = 0; p < 20; ++p)
            s = fmaf(Wc[c*20 + p], W3[400 + p*20 + i], s);
        W[OFF_M3 + r] = s;
    } else if (idx < 480) {
        const int j = idx - 460;
        W[OFF_E1 + j] = b2[j] + b3[j];
    }
}

// ---- prep2: final folded weights (reads G2/M3/e1 from d_ws) ----
__global__ void prep2_kernel(const float* __restrict__ Wv, const float* __restrict__ Wres,
                             const float* __restrict__ W1, const float* __restrict__ b1,
                             const float* __restrict__ W2, const float* __restrict__ b2,
                             const float* __restrict__ b3, const float* __restrict__ Wc,
                             const float* __restrict__ bc, const float* __restrict__ W3,
                             float* __restrict__ W) {
    const float* G2 = W + OFF_G2;
    const float* M3 = W + OFF_M3;
    const float* e1 = W + OFF_E1;
    for (int idx = blockIdx.x * blockDim.x + threadIdx.x; idx < NW; idx += gridDim.x * blockDim.x) {
        float s = 0.f;
        if (idx < 400) {                               // G1[k][m], layer-0 fold
            const int k = idx / 20, m = idx % 20;
            for (int j = 0; j < 20; ++j)
                s = fmaf(Wv[j*20 + k] + Wres[k*20 + j], W1[m*20 + j], s);
        } else if (idx < 800) {                        // P1[m'][m] = sum_i W2_0[i][m'] G2[i][m]
            const int r = idx - 400, mp = r / 20, m = r % 20;
            for (int i = 0; i < 20; ++i)
                s = fmaf(W2[i*20 + mp], G2[i*20 + m], s);
        } else if (idx < 1200) {                       // P2[k][m] = sum_i W3_0[i][k] G2[i][m]
            const int r = idx - 800, k = r / 20, m = r % 20;
            for (int i = 0; i < 20; ++i)
                s = fmaf(W3[i*20 + k], G2[i*20 + m], s);
        } else if (idx < 1280) {                       // Q1p[m'][c] = sum_i W2_0[i][m'] M3[i][c]
            const int r = idx - 1200, k = r >> 2, c = r & 3;
            if (c < 3)
                for (int i = 0; i < 20; ++i)
                    s = fmaf(W2[i*20 + k], M3[i*3 + c], s);
        } else if (idx < 1360) {                       // Q2p[k][c] = sum_i W3_0[i][k] M3[i][c]
            const int r = idx - 1280, k = r >> 2, c = r & 3;
            if (c < 3)
                for (int i = 0; i < 20; ++i)
                    s = fmaf(W3[i*20 + k], M3[i*3 + c], s);
        } else if (idx < 1440) {                       // M2p[m][c] = sum_p Wc[c][p] W2_1[p][m]
            const int r = idx - 1360, m = r >> 2, c = r & 3;
            if (c < 3)
                for (int p = 0; p < 20; ++p)
                    s = fmaf(Wc[c*20 + p], W2[400 + p*20 + m], s);
        } else if (idx < 1460) {                       // b11
            s = b1[idx - 1440];
        } else if (idx < 1480) {                       // F2[m] = b1_1[m] + e1@G2
            const int m = idx - 1460;
            s = b1[20 + m];
            for (int i = 0; i < 20; ++i)
                s = fmaf(e1[i], G2[i*20 + m], s);
        } else {                                       // F3p[c]
            const int c = idx - 1480;
            if (c < 3) {
                s = bc[c];
                for (int p = 0; p < 20; ++p)
                    s = fmaf(Wc[c*20 + p], b2[20 + p] + b3[20 + p], s);
                for (int i = 0; i < 20; ++i)
                    s = fmaf(e1[i], M3[i*3 + c], s);
            }
        }
        W[idx] = s;
    }
}

// T=4 token blocking: every ds_read_b128 weight broadcast feeds 16 FMAs.
// x is NOT kept resident for layer 2 — it is re-streamed from global (L2-hit,
// vmem pipe is nearly idle) to keep VGPRs ~190 (2 waves/SIMD, no spill).
__global__ __launch_bounds__(256, 2) void fwd_kernel(const float* __restrict__ X,
                                                     const float* __restrict__ Wg,
                                                     float* __restrict__ out, int nquad) {
    __shared__ float Ws[NW];
    for (int i = threadIdx.x; i < NW; i += 256) Ws[i] = Wg[i];
    __syncthreads();

    const int q4 = blockIdx.x * 256 + threadIdx.x;
    if (q4 >= nquad) return;
    const float4* W4 = reinterpret_cast<const float4*>(Ws);
    const float* xbase = X + (size_t)q4 * 80;     // 4 tokens x 20 floats

    // ---------- stage 1: h = relu(x @ G1 + b11) ----------
    float h[4][20];
    #pragma unroll
    for (int r = 0; r < 5; ++r) {
        const float4 b = W4[OFF_B11/4 + r];
        #pragma unroll
        for (int t = 0; t < 4; ++t) {
            h[t][4*r+0] = b.x; h[t][4*r+1] = b.y; h[t][4*r+2] = b.z; h[t][4*r+3] = b.w;
        }
    }
    #pragma unroll 1
    for (int q = 0; q < 5; ++q) {
        float xr[4][4];
        #pragma unroll
        for (int t = 0; t < 4; ++t) {
            const float4 v = *reinterpret_cast<const float4*>(xbase + t*20 + q*4);
            xr[t][0] = v.x; xr[t][1] = v.y; xr[t][2] = v.z; xr[t][3] = v.w;
        }
        #pragma unroll
        for (int kk = 0; kk < 4; ++kk) {
            const int k = q*4 + kk;
            #pragma unroll
            for (int r = 0; r < 5; ++r) {
                const float4 w = W4[OFF_G1/4 + k*5 + r];
                #pragma unroll
                for (int t = 0; t < 4; ++t) {
                    h[t][4*r+0] = fmaf(xr[t][kk], w.x, h[t][4*r+0]);
                    h[t][4*r+1] = fmaf(xr[t][kk], w.y, h[t][4*r+1]);
                    h[t][4*r+2] = fmaf(xr[t][kk], w.z, h[t][4*r+2]);
                    h[t][4*r+3] = fmaf(xr[t][kk], w.w, h[t][4*r+3]);
                }
            }
        }
    }
    #pragma unroll
    for (int t = 0; t < 4; ++t)
        #pragma unroll
        for (int i = 0; i < 20; ++i) h[t][i] = fmaxf(h[t][i], 0.f);

    // ---------- stage 2a: gp = F2 + h @ P1 ; l = F3 + h @ Q1 ----------
    float gp[4][20];
    float l[4][3];
    #pragma unroll
    for (int r = 0; r < 5; ++r) {
        const float4 b = W4[OFF_F2/4 + r];
        #pragma unroll
        for (int t = 0; t < 4; ++t) {
            gp[t][4*r+0] = b.x; gp[t][4*r+1] = b.y; gp[t][4*r+2] = b.z; gp[t][4*r+3] = b.w;
        }
    }
    {
        const float4 f3 = W4[OFF_F3/4];
        #pragma unroll
        for (int t = 0; t < 4; ++t) { l[t][0] = f3.x; l[t][1] = f3.y; l[t][2] = f3.z; }
    }
    #pragma unroll 2
    for (int k = 0; k < 20; ++k) {
        float hk[4];
        #pragma unroll
        for (int t = 0; t < 4; ++t) hk[t] = h[t][k];
        #pragma unroll
        for (int r = 0; r < 5; ++r) {
            const float4 w = W4[OFF_P1/4 + k*5 + r];
            #pragma unroll
            for (int t = 0; t < 4; ++t) {
                gp[t][4*r+0] = fmaf(hk[t], w.x, gp[t][4*r+0]);
                gp[t][4*r+1] = fmaf(hk[t], w.y, gp[t][4*r+1]);
                gp[t][4*r+2] = fmaf(hk[t], w.z, gp[t][4*r+2]);
                gp[t][4*r+3] = fmaf(hk[t], w.w, gp[t][4*r+3]);
            }
        }
        const float4 wq = W4[OFF_Q1/4 + k];
        #pragma unroll
        for (int t = 0; t < 4; ++t) {
            l[t][0] = fmaf(hk[t], wq.x, l[t][0]);
            l[t][1] = fmaf(hk[t], wq.y, l[t][1]);
            l[t][2] = fmaf(hk[t], wq.z, l[t][2]);
        }
    }

    // ---------- stage 2b: gp += x @ P2 ; l += x @ Q2  (x re-streamed) ----------
    #pragma unroll 1
    for (int q = 0; q < 5; ++q) {
        float xr[4][4];
        #pragma unroll
        for (int t = 0; t < 4; ++t) {
            const float4 v = *reinterpret_cast<const float4*>(xbase + t*20 + q*4);
            xr[t][0] = v.x; xr[t][1] = v.y; xr[t][2] = v.z; xr[t][3] = v.w;
        }
        #pragma unroll
        for (int kk = 0; kk < 4; ++kk) {
            const int k = q*4 + kk;
            #pragma unroll
            for (int r = 0; r < 5; ++r) {
                const float4 w = W4[OFF_P2/4 + k*5 + r];
                #pragma unroll
                for (int t = 0; t < 4; ++t) {
                    gp[t][4*r+0] = fmaf(xr[t][kk], w.x, gp[t][4*r+0]);
                    gp[t][4*r+1] = fmaf(xr[t][kk], w.y, gp[t][4*r+1]);
                    gp[t][4*r+2] = fmaf(xr[t][kk], w.z, gp[t][4*r+2]);
                    gp[t][4*r+3] = fmaf(xr[t][kk], w.w, gp[t][4*r+3]);
                }
            }
            const float4 wq = W4[OFF_Q2/4 + k];
            #pragma unroll
            for (int t = 0; t < 4; ++t) {
                l[t][0] = fmaf(xr[t][kk], wq.x, l[t][0]);
                l[t][1] = fmaf(xr[t][kk], wq.y, l[t][1]);
                l[t][2] = fmaf(xr[t][kk], wq.z, l[t][2]);
            }
        }
    }

    // ---------- stage 3: g = relu(gp); l += g @ M2 ----------
    #pragma unroll 4
    for (int k = 0; k < 20; ++k) {
        const float4 wm = W4[OFF_M2/4 + k];
        #pragma unroll
        for (int t = 0; t < 4; ++t) {
            const float gk = fmaxf(gp[t][k], 0.f);
            l[t][0] = fmaf(gk, wm.x, l[t][0]);
            l[t][1] = fmaf(gk, wm.y, l[t][1]);
            l[t][2] = fmaf(gk, wm.z, l[t][2]);
        }
    }

    // ---------- softmax + store (4 tokens x 3 = 12 floats = 3 float4) ----------
    float o[12];
    #pragma unroll
    for (int t = 0; t < 4; ++t) {
        const float m  = fmaxf(fmaxf(l[t][0], l[t][1]), l[t][2]);
        const float e0 = __expf(l[t][0] - m);
        const float e1 = __expf(l[t][1] - m);
        const float e2 = __expf(l[t][2] - m);
        const float r  = 1.f / (e0 + e1 + e2);
        o[3*t+0] = e0 * r; o[3*t+1] = e1 * r; o[3*t+2] = e2 * r;
    }
    float4* o4 = reinterpret_cast<float4*>(out + (size_t)q4 * 12);
    o4[0] = make_float4(o[0], o[1], o[2],  o[3]);
    o4[1] = make_float4(o[4], o[5], o[6],  o[7]);
    o4[2] = make_float4(o[8], o[9], o[10], o[11]);
}

extern "C" void kernel_launch(void* const* d_in, const int* in_sizes, int n_in,
                              void* d_out, int out_size, void* d_ws, size_t ws_size,
                              hipStream_t stream) {
    const float* X    = (const float*)d_in[0];
    // d_in[1]=Wq, d_in[2]=Wk: dead (softmax over singleton axis == 1)
    const float* Wv   = (const float*)d_in[3];
    const float* Wres = (const float*)d_in[4];
    const float* W1   = (const float*)d_in[5];
    const float* b1   = (const float*)d_in[6];
    const float* W2   = (const float*)d_in[7];
    const float* b2   = (const float*)d_in[8];
    const float* W3   = (const float*)d_in[9];
    const float* b3   = (const float*)d_in[10];
    const float* Wc   = (const float*)d_in[11];
    const float* bc   = (const float*)d_in[12];
    float* out = (float*)d_out;
    float* W   = (float*)d_ws;

    const int S = in_sizes[0] / 20;
    const int nquad = S / 4;                    // S = 2^20, divides evenly

    prep1_kernel<<<1, 512, 0, stream>>>(Wv, Wres, W1, b2, b3, Wc, W3, W);
    prep2_kernel<<<4, 256, 0, stream>>>(Wv, Wres, W1, b1, W2, b2, b3, Wc, bc, W3, W);

    const int block = 256;
    const int grid = (nquad + block - 1) / block;
    fwd_kernel<<<grid, block, 0, stream>>>(X, W, out, nquad);
}

// Round 4
// 200.754 us; speedup vs baseline: 1.4095x; 1.4095x over previous
//
#include <hip/hip_runtime.h>
#include <math.h>

// Folded model (exact algebra, per-token):
//   h      = relu(x @ G1 + b11)                      [400 MACs]
//   g      = relu(h @ P1 + x @ P2 + F2)              [800 MACs]
//   logits = g @ M2 + h @ Q1 + x @ Q2 + F3           [180 MACs]
//   out    = softmax(logits)
// Weight layouts padded so every LDS weight access is a ds_read_b128.

#define OFF_G1   0      // [20][20] row k (x index)
#define OFF_P1   400    // [20][20] row m' (h index)
#define OFF_P2   800    // [20][20] row k (x index)
#define OFF_Q1   1200   // [20][4]  row m' : {Q1[m'][0..2], 0}
#define OFF_Q2   1280   // [20][4]  row k
#define OFF_M2   1360   // [20][4]  row m (g index)
#define OFF_B11  1440   // [20]
#define OFF_F2   1460   // [20]
#define OFF_F3   1480   // [4] {f3[0..2], 0}
#define NW       1484
// scratch (in d_ws, beyond the weight block)
#define OFF_G2   1536   // [20][20] G2[i][m]
#define OFF_M3   1936   // [20][3]  M3[i][c]
#define OFF_E1   1996   // [20]

// ---- prep1: layer-1 folds into d_ws scratch ----
__global__ void prep1_kernel(const float* __restrict__ Wv, const float* __restrict__ Wres,
                             const float* __restrict__ W1, const float* __restrict__ b2,
                             const float* __restrict__ b3, const float* __restrict__ Wc,
                             const float* __restrict__ W3, float* __restrict__ W) {
    const int idx = threadIdx.x;
    if (idx < 400) {
        const int i = idx / 20, m = idx % 20;
        float s = 0.f;
        for (int j = 0; j < 20; ++j)
            s = fmaf(Wv[400 + j*20 + i] + Wres[400 + i*20 + j], W1[400 + m*20 + j], s);
        W[OFF_G2 + idx] = s;
    } else if (idx < 460) {
        const int r = idx - 400, i = r / 3, c = r % 3;
        float s = 0.f;
        for (int p = 0; p < 20; ++p)
            s = fmaf(Wc[c*20 + p], W3[400 + p*20 + i], s);
        W[OFF_M3 + r] = s;
    } else if (idx < 480) {
        const int j = idx - 460;
        W[OFF_E1 + j] = b2[j] + b3[j];
    }
}

// ---- prep2: final folded weights (reads G2/M3/e1 from d_ws) ----
__global__ void prep2_kernel(const float* __restrict__ Wv, const float* __restrict__ Wres,
                             const float* __restrict__ W1, const float* __restrict__ b1,
                             const float* __restrict__ W2, const float* __restrict__ b2,
                             const float* __restrict__ b3, const float* __restrict__ Wc,
                             const float* __restrict__ bc, const float* __restrict__ W3,
                             float* __restrict__ W) {
    const float* G2 = W + OFF_G2;
    const float* M3 = W + OFF_M3;
    const float* e1 = W + OFF_E1;
    for (int idx = blockIdx.x * blockDim.x + threadIdx.x; idx < NW; idx += gridDim.x * blockDim.x) {
        float s = 0.f;
        if (idx < 400) {                               // G1[k][m], layer-0 fold
            const int k = idx / 20, m = idx % 20;
            for (int j = 0; j < 20; ++j)
                s = fmaf(Wv[j*20 + k] + Wres[k*20 + j], W1[m*20 + j], s);
        } else if (idx < 800) {                        // P1[m'][m] = sum_i W2_0[i][m'] G2[i][m]
            const int r = idx - 400, mp = r / 20, m = r % 20;
            for (int i = 0; i < 20; ++i)
                s = fmaf(W2[i*20 + mp], G2[i*20 + m], s);
        } else if (idx < 1200) {                       // P2[k][m] = sum_i W3_0[i][k] G2[i][m]
            const int r = idx - 800, k = r / 20, m = r % 20;
            for (int i = 0; i < 20; ++i)
                s = fmaf(W3[i*20 + k], G2[i*20 + m], s);
        } else if (idx < 1280) {                       // Q1p[m'][c] = sum_i W2_0[i][m'] M3[i][c]
            const int r = idx - 1200, k = r >> 2, c = r & 3;
            if (c < 3)
                for (int i = 0; i < 20; ++i)
                    s = fmaf(W2[i*20 + k], M3[i*3 + c], s);
        } else if (idx < 1360) {                       // Q2p[k][c] = sum_i W3_0[i][k] M3[i][c]
            const int r = idx - 1280, k = r >> 2, c = r & 3;
            if (c < 3)
                for (int i = 0; i < 20; ++i)
                    s = fmaf(W3[i*20 + k], M3[i*3 + c], s);
        } else if (idx < 1440) {                       // M2p[m][c] = sum_p Wc[c][p] W2_1[p][m]
            const int r = idx - 1360, m = r >> 2, c = r & 3;
            if (c < 3)
                for (int p = 0; p < 20; ++p)
                    s = fmaf(Wc[c*20 + p], W2[400 + p*20 + m], s);
        } else if (idx < 1460) {                       // b11
            s = b1[idx - 1440];
        } else if (idx < 1480) {                       // F2[m] = b1_1[m] + e1@G2
            const int m = idx - 1460;
            s = b1[20 + m];
            for (int i = 0; i < 20; ++i)
                s = fmaf(e1[i], G2[i*20 + m], s);
        } else {                                       // F3p[c]
            const int c = idx - 1480;
            if (c < 3) {
                s = bc[c];
                for (int p = 0; p < 20; ++p)
                    s = fmaf(Wc[c*20 + p], b2[20 + p] + b3[20 + p], s);
                for (int i = 0; i < 20; ++i)
                    s = fmaf(e1[i], M3[i*3 + c], s);
            }
        }
        W[idx] = s;
    }
}

// T=4 token blocking, ALL register-array indices compile-time (full unroll on
// any loop whose variable indexes h[][]/gp[][] — round-3's partial unrolls
// demoted those arrays to scratch: 469 MB spill writes). Weights in LDS as
// broadcast ds_read_b128; x re-streamed from global for stage 2b.
__global__ __launch_bounds__(256, 2) void fwd_kernel(const float* __restrict__ X,
                                                     const float* __restrict__ Wg,
                                                     float* __restrict__ out, int nquad) {
    __shared__ float Ws[NW];
    for (int i = threadIdx.x; i < NW; i += 256) Ws[i] = Wg[i];
    __syncthreads();

    const int q4 = blockIdx.x * 256 + threadIdx.x;
    if (q4 >= nquad) return;
    const float4* W4 = reinterpret_cast<const float4*>(Ws);
    const float* xbase = X + (size_t)q4 * 80;     // 4 tokens x 20 floats

    // ---------- stage 1: h = relu(x @ G1 + b11) ----------
    float h[4][20];
    #pragma unroll
    for (int r = 0; r < 5; ++r) {
        const float4 b = W4[OFF_B11/4 + r];
        #pragma unroll
        for (int t = 0; t < 4; ++t) {
            h[t][4*r+0] = b.x; h[t][4*r+1] = b.y; h[t][4*r+2] = b.z; h[t][4*r+3] = b.w;
        }
    }
    #pragma unroll 1
    for (int q = 0; q < 5; ++q) {
        float xr[4][4];
        #pragma unroll
        for (int t = 0; t < 4; ++t) {
            const float4 v = *reinterpret_cast<const float4*>(xbase + t*20 + q*4);
            xr[t][0] = v.x; xr[t][1] = v.y; xr[t][2] = v.z; xr[t][3] = v.w;
        }
        #pragma unroll
        for (int kk = 0; kk < 4; ++kk) {
            const int k = q*4 + kk;                 // runtime: LDS address only
            #pragma unroll
            for (int r = 0; r < 5; ++r) {
                const float4 w = W4[OFF_G1/4 + k*5 + r];
                #pragma unroll
                for (int t = 0; t < 4; ++t) {
                    h[t][4*r+0] = fmaf(xr[t][kk], w.x, h[t][4*r+0]);
                    h[t][4*r+1] = fmaf(xr[t][kk], w.y, h[t][4*r+1]);
                    h[t][4*r+2] = fmaf(xr[t][kk], w.z, h[t][4*r+2]);
                    h[t][4*r+3] = fmaf(xr[t][kk], w.w, h[t][4*r+3]);
                }
            }
        }
    }
    #pragma unroll
    for (int t = 0; t < 4; ++t)
        #pragma unroll
        for (int i = 0; i < 20; ++i) h[t][i] = fmaxf(h[t][i], 0.f);

    // ---------- stage 2a: gp = F2 + h @ P1 ; l = F3 + h @ Q1 (k FULLY unrolled) ----------
    float gp[4][20];
    float l[4][3];
    #pragma unroll
    for (int r = 0; r < 5; ++r) {
        const float4 b = W4[OFF_F2/4 + r];
        #pragma unroll
        for (int t = 0; t < 4; ++t) {
            gp[t][4*r+0] = b.x; gp[t][4*r+1] = b.y; gp[t][4*r+2] = b.z; gp[t][4*r+3] = b.w;
        }
    }
    {
        const float4 f3 = W4[OFF_F3/4];
        #pragma unroll
        for (int t = 0; t < 4; ++t) { l[t][0] = f3.x; l[t][1] = f3.y; l[t][2] = f3.z; }
    }
    #pragma unroll
    for (int k = 0; k < 20; ++k) {
        #pragma unroll
        for (int r = 0; r < 5; ++r) {
            const float4 w = W4[OFF_P1/4 + k*5 + r];
            #pragma unroll
            for (int t = 0; t < 4; ++t) {
                gp[t][4*r+0] = fmaf(h[t][k], w.x, gp[t][4*r+0]);
                gp[t][4*r+1] = fmaf(h[t][k], w.y, gp[t][4*r+1]);
                gp[t][4*r+2] = fmaf(h[t][k], w.z, gp[t][4*r+2]);
                gp[t][4*r+3] = fmaf(h[t][k], w.w, gp[t][4*r+3]);
            }
        }
        const float4 wq = W4[OFF_Q1/4 + k];
        #pragma unroll
        for (int t = 0; t < 4; ++t) {
            l[t][0] = fmaf(h[t][k], wq.x, l[t][0]);
            l[t][1] = fmaf(h[t][k], wq.y, l[t][1]);
            l[t][2] = fmaf(h[t][k], wq.z, l[t][2]);
        }
    }

    // ---------- stage 2b: gp += x @ P2 ; l += x @ Q2  (x re-streamed) ----------
    #pragma unroll 1
    for (int q = 0; q < 5; ++q) {
        float xr[4][4];
        #pragma unroll
        for (int t = 0; t < 4; ++t) {
            const float4 v = *reinterpret_cast<const float4*>(xbase + t*20 + q*4);
            xr[t][0] = v.x; xr[t][1] = v.y; xr[t][2] = v.z; xr[t][3] = v.w;
        }
        #pragma unroll
        for (int kk = 0; kk < 4; ++kk) {
            const int k = q*4 + kk;                 // runtime: LDS address only
            #pragma unroll
            for (int r = 0; r < 5; ++r) {
                const float4 w = W4[OFF_P2/4 + k*5 + r];
                #pragma unroll
                for (int t = 0; t < 4; ++t) {
                    gp[t][4*r+0] = fmaf(xr[t][kk], w.x, gp[t][4*r+0]);
                    gp[t][4*r+1] = fmaf(xr[t][kk], w.y, gp[t][4*r+1]);
                    gp[t][4*r+2] = fmaf(xr[t][kk], w.z, gp[t][4*r+2]);
                    gp[t][4*r+3] = fmaf(xr[t][kk], w.w, gp[t][4*r+3]);
                }
            }
            const float4 wq = W4[OFF_Q2/4 + k];
            #pragma unroll
            for (int t = 0; t < 4; ++t) {
                l[t][0] = fmaf(xr[t][kk], wq.x, l[t][0]);
                l[t][1] = fmaf(xr[t][kk], wq.y, l[t][1]);
                l[t][2] = fmaf(xr[t][kk], wq.z, l[t][2]);
            }
        }
    }

    // ---------- stage 3: g = relu(gp); l += g @ M2 (k FULLY unrolled) ----------
    #pragma unroll
    for (int k = 0; k < 20; ++k) {
        const float4 wm = W4[OFF_M2/4 + k];
        #pragma unroll
        for (int t = 0; t < 4; ++t) {
            const float gk = fmaxf(gp[t][k], 0.f);
            l[t][0] = fmaf(gk, wm.x, l[t][0]);
            l[t][1] = fmaf(gk, wm.y, l[t][1]);
            l[t][2] = fmaf(gk, wm.z, l[t][2]);
        }
    }

    // ---------- softmax + store (4 tokens x 3 = 12 floats = 3 float4) ----------
    float o[12];
    #pragma unroll
    for (int t = 0; t < 4; ++t) {
        const float m  = fmaxf(fmaxf(l[t][0], l[t][1]), l[t][2]);
        const float e0 = __expf(l[t][0] - m);
        const float e1 = __expf(l[t][1] - m);
        const float e2 = __expf(l[t][2] - m);
        const float r  = 1.f / (e0 + e1 + e2);
        o[3*t+0] = e0 * r; o[3*t+1] = e1 * r; o[3*t+2] = e2 * r;
    }
    float4* o4 = reinterpret_cast<float4*>(out + (size_t)q4 * 12);
    o4[0] = make_float4(o[0], o[1], o[2],  o[3]);
    o4[1] = make_float4(o[4], o[5], o[6],  o[7]);
    o4[2] = make_float4(o[8], o[9], o[10], o[11]);
}

extern "C" void kernel_launch(void* const* d_in, const int* in_sizes, int n_in,
                              void* d_out, int out_size, void* d_ws, size_t ws_size,
                              hipStream_t stream) {
    const float* X    = (const float*)d_in[0];
    // d_in[1]=Wq, d_in[2]=Wk: dead (softmax over singleton axis == 1)
    const float* Wv   = (const float*)d_in[3];
    const float* Wres = (const float*)d_in[4];
    const float* W1   = (const float*)d_in[5];
    const float* b1   = (const float*)d_in[6];
    const float* W2   = (const float*)d_in[7];
    const float* b2   = (const float*)d_in[8];
    const float* W3   = (const float*)d_in[9];
    const float* b3   = (const float*)d_in[10];
    const float* Wc   = (const float*)d_in[11];
    const float* bc   = (const float*)d_in[12];
    float* out = (float*)d_out;
    float* W   = (float*)d_ws;

    const int S = in_sizes[0] / 20;
    const int nquad = S / 4;                    // S = 2^20, divides evenly

    prep1_kernel<<<1, 512, 0, stream>>>(Wv, Wres, W1, b2, b3, Wc, W3, W);
    prep2_kernel<<<4, 256, 0, stream>>>(Wv, Wres, W1, b1, W2, b2, b3, Wc, bc, W3, W);

    const int block = 256;
    const int grid = (nquad + block - 1) / block;
    fwd_kernel<<<grid, block, 0, stream>>>(X, W, out, nquad);
}